// Round 17
// baseline (4150.420 us; speedup 1.0000x reference)
//
#include <hip/hip_runtime.h>
#include <hip/hip_bf16.h>
#include <hip/hip_fp8.h>

#define BETA_C 0.04f
#define EPS_LOW_C 0.2f
#define EPS_HIGH_C 0.2f

static constexpr int B_ = 4, S_ = 1024, H_ = 2048, V_ = 32000;
static constexpr int M_ = B_ * S_;          // 4096 token rows
static constexpr int BM = 256, BN = 256, BK = 128;   // BK in fp8 elements == bytes
static constexpr int NRB = M_ / BM;         // 16
static constexpr int NCB = V_ / BN;         // 125
static constexpr int NT  = H_ / BK;         // 16 K-steps

typedef __attribute__((ext_vector_type(4))) int   i32x4;
typedef __attribute__((ext_vector_type(8))) int   i32x8;
typedef __attribute__((ext_vector_type(4))) float f32x4;

__device__ __forceinline__ unsigned int q8(float v) {
    __hip_fp8_e4m3 t(v);            // OCP e4m3fn, RNE + saturate
    return (unsigned int)t.__x;
}

__device__ __forceinline__ void gload_lds16(const unsigned char* g, char* l) {
    __builtin_amdgcn_global_load_lds(
        (const __attribute__((address_space(1))) unsigned int*)g,
        (__attribute__((address_space(3))) unsigned int*)l, 16, 0, 0);
}

// ---------------- fp32 -> fp8 e4m3 conversion (x: scale 1; W: scale 32) -------------
__global__ void cvt_fp8_kernel(const float* __restrict__ in, uint2* __restrict__ out,
                               int n8, float scale) {
    int i = blockIdx.x * blockDim.x + threadIdx.x;
    int stride = gridDim.x * blockDim.x;
    for (; i < n8; i += stride) {
        float4 a = reinterpret_cast<const float4*>(in)[2 * i];
        float4 b = reinterpret_cast<const float4*>(in)[2 * i + 1];
        uint2 w;
        w.x = q8(a.x * scale) | (q8(a.y * scale) << 8) | (q8(a.z * scale) << 16) | (q8(a.w * scale) << 24);
        w.y = q8(b.x * scale) | (q8(b.y * scale) << 8) | (q8(b.z * scale) << 16) | (q8(b.w * scale) << 24);
        out[i] = w;
    }
}

// ---------------- 256x256 fused GEMM (MX-fp8 16x16x128) + exp-sum + selected logit ----
// r16 body verbatim; ONLY change: __launch_bounds__(512, 1). r15/r16's 4.8GB scratch
// was acc spilling: scale-MFMA keeps C/D in arch VGPRs (bf16 uses AGPRs), and the
// (512,2) bound capped arch VGPRs at 128 < acc(128)+frags(64)+addr. Cap 512 lets the
// allocator take ~220; LDS (160KB, 1 block/CU) still fixes occupancy at 2 waves/SIMD.
__global__ __launch_bounds__(512, 1) void gemm_lse_kernel(
    const unsigned char* __restrict__ A,
    const unsigned char* __restrict__ W,
    const float* __restrict__ bias,
    const int* __restrict__ sel,
    float* __restrict__ partials,     // [M][NCB]
    float* __restrict__ sel_logit)    // [M]
{
    __shared__ __attribute__((aligned(128))) char lds[163840]; // A:0,32K  B:64K,96K,128K

    const int bid = blockIdx.x;
    const int swz = (bid & 7) * (NRB * NCB / 8) + (bid >> 3);   // 2000 % 8 == 0: bijective
    const int brow = swz % NRB;
    const int bcol = swz / NRB;
    const int tid  = threadIdx.x;
    const int lane = tid & 63;
    const int wv   = tid >> 6;
    const int wm   = wv >> 2;        // 0..1  row half (128 rows)
    const int wn   = wv & 3;         // 0..3  col quarter (64 cols)
    const int l15  = lane & 15, lg = lane >> 4;

    // ---- LDS read bases: row*128B + swizzled 16B slot; j=0/1 = k-lo/k-hi 16B ----
    int aBase[2], bBase[2];
    #pragma unroll
    for (int j = 0; j < 2; ++j) {
        const int sw = ((2 * lg + j) ^ (l15 & 7)) << 4;
        aBase[j] = (wm * 128 + l15) * 128 + sw;
        bBase[j] = (wn * 64 + l15) * 128 + sw;
    }
    // ---- stage per-lane global byte offsets; source 16B granule inverse-swizzled ----
    int sByte[4];
    #pragma unroll
    for (int i = 0; i < 4; ++i) {
        int c = i * 512 + tid;       // 0..2047 chunks of the 32KB tile
        int r = c >> 3;              // 0..255
        int gg = (c & 7) ^ (r & 7);
        sByte[i] = r * 2048 + gg * 16;   // global row stride = 2048 B (fp8)
    }

    const unsigned char* Ab = A + (long)brow * BM * H_;
    const unsigned char* Wb = W + (long)bcol * BN * H_;

    const int sc = 0x7F7F7F7F;       // e8m0 = 127 -> 2^0 in all 4 bytes (opsel-proof)

    f32x4 acc[8][4] = {};
    i32x8 afA[2], afB[2], bf[4];     // ping-pong A fragments

#define STG(gb, bufoff, ktb) \
    { _Pragma("unroll") \
      for (int i_ = 0; i_ < 4; ++i_) \
          gload_lds16((gb) + sByte[i_] + (ktb), \
                      lds + (bufoff) + (i_ * 512 + tid) * 16); }

#define RDA(abuf, q, dst) \
    { _Pragma("unroll") \
      for (int mi_ = 0; mi_ < 2; ++mi_) { \
          i32x4 lo_ = *(const i32x4*)(lds + (abuf) + ((q) * 2 + mi_) * 2048 + aBase[0]); \
          i32x4 hi_ = *(const i32x4*)(lds + (abuf) + ((q) * 2 + mi_) * 2048 + aBase[1]); \
          dst[mi_] = __builtin_shufflevector(lo_, hi_, 0, 1, 2, 3, 4, 5, 6, 7); } }

#define RDB(bbuf) \
    { _Pragma("unroll") \
      for (int n_ = 0; n_ < 4; ++n_) { \
          i32x4 lo_ = *(const i32x4*)(lds + (bbuf) + n_ * 2048 + bBase[0]); \
          i32x4 hi_ = *(const i32x4*)(lds + (bbuf) + n_ * 2048 + bBase[1]); \
          bf[n_] = __builtin_shufflevector(lo_, hi_, 0, 1, 2, 3, 4, 5, 6, 7); } }

#define MM(q, afr) \
    __builtin_amdgcn_s_setprio(1); \
    _Pragma("unroll") \
    for (int mi_ = 0; mi_ < 2; ++mi_) \
    _Pragma("unroll") \
    for (int n_ = 0; n_ < 4; ++n_) \
        acc[(q) * 2 + mi_][n_] = __builtin_amdgcn_mfma_scale_f32_16x16x128_f8f6f4( \
            afr[mi_], bf[n_], acc[(q) * 2 + mi_][n_], 0, 0, 0, sc, 0, sc); \
    __builtin_amdgcn_s_setprio(0);

#define LGKM(n) asm volatile("s_waitcnt lgkmcnt(" #n ")" ::: "memory"); \
    __builtin_amdgcn_sched_barrier(0);
#define VMC(n)  asm volatile("s_waitcnt vmcnt(" #n ")" ::: "memory");
#define BAR     { __builtin_amdgcn_s_barrier(); __builtin_amdgcn_sched_barrier(0); }
#define SCB     __builtin_amdgcn_sched_barrier(0);

    // ---- prologue: A(0)->a0, B(0)->b0, B(1)->b1  (12 loads) ----
    STG(Ab, 0, 0)
    STG(Wb, 65536, 0)
    STG(Wb, 98304, 128)
    VMC(4)                      // A(0),B(0) landed; B(1) may fly
    BAR

    #pragma unroll
    for (int t = 0; t < NT; ++t) {
        const int aR  = (t & 1) * 32768;               // A read buf (t)
        const int aW  = ((t + 1) & 1) * 32768;         // A write buf (t+1)
        const int bR  = 65536 + (t % 3) * 32768;       // B read buf (t)
        const int bW  = 65536 + ((t + 2) % 3) * 32768; // B write buf (t+2)
        const int ktA = ((t + 1) * BK) & (H_ - 1);     // bytes; tail wraps (dead-safe)
        const int ktB = ((t + 2) * BK) & (H_ - 1);

        // read groups (ds FIFO in-order; groups pinned by SCB)
        RDB(bR) RDA(aR, 0, afA)      // g1: 12 reads
        SCB
        RDA(aR, 1, afB)              // g2: 4
        SCB
        // stages (vmcnt only): A(t+1), B(t+2)
        STG(Ab, aW, ktA)
        STG(Wb, bW, ktB)
        // MFMA clusters overlapped with remaining read drain
        LGKM(4)   // g1 (B + q0) done; g2 may fly
        MM(0, afA)
        RDA(aR, 2, afA)              // g3: 4 (drains under MM0; WAR on afA is safe)
        SCB
        LGKM(4)   // g2 done
        MM(1, afB)
        RDA(aR, 3, afB)              // g4: 4 (drains under MM1)
        SCB
        LGKM(4)   // g3 done
        MM(2, afA)
        LGKM(0)   // g4 done; all step-t LDS reads drained before barrier
        MM(3, afB)
        // boundary: newest 4 vm-ops = B(t+2); forces A(t+1), B(t+1) landed.
        VMC(4)
        BAR
    }

    VMC(0)
    __syncthreads();

    // ---- epilogue: dequant (x1/32), bias, exp, row partial sums, selected logit ----
    float* sums = (float*)lds;                     // [256][4], LDS now free
    const int colb = bcol * BN + wn * 64 + l15;    // + n*16
    float bv[4];
    #pragma unroll
    for (int n = 0; n < 4; ++n) bv[n] = bias[colb + n * 16];

    #pragma unroll
    for (int m = 0; m < 8; ++m) {
        #pragma unroll
        for (int j = 0; j < 4; ++j) {
            const long grow = (long)brow * BM + wm * 128 + m * 16 + lg * 4 + j;
            const int stok = sel[grow];
            float s = 0.f;
            #pragma unroll
            for (int n = 0; n < 4; ++n) {
                float logit = acc[m][n][j] * 0.03125f + bv[n];
                s += __expf(logit);
                if (stok == colb + n * 16) sel_logit[grow] = logit;
            }
            s += __shfl_xor(s, 1); s += __shfl_xor(s, 2);
            s += __shfl_xor(s, 4); s += __shfl_xor(s, 8);
            if (l15 == 0) sums[(wm * 128 + m * 16 + lg * 4 + j) * 4 + wn] = s;
        }
    }
    __syncthreads();
    if (tid < BM) {
        float tot = sums[tid * 4 + 0] + sums[tid * 4 + 1] + sums[tid * 4 + 2] + sums[tid * 4 + 3];
        partials[((long)brow * BM + tid) * NCB + bcol] = tot;
    }
#undef STG
#undef RDA
#undef RDB
#undef MM
#undef LGKM
#undef VMC
#undef BAR
#undef SCB
}

// ---------------- per-row reduce: partials -> per-token logp ----------------
__global__ void reduce_lse_kernel(const float* __restrict__ partials,
                                  const float* __restrict__ sel_logit,
                                  float* __restrict__ lp) {
    const int row = blockIdx.x;
    const int lane = threadIdx.x;   // 64
    float s = 0.f;
    for (int i = lane; i < NCB; i += 64) s += partials[(long)row * NCB + i];
    #pragma unroll
    for (int o = 32; o; o >>= 1) s += __shfl_xor(s, o);
    if (lane == 0) lp[row] = sel_logit[row] - __logf(s);
}

// ---------------- final GSPO loss (one block) ----------------
__device__ __forceinline__ float block_sum(float v, float* red) {
    const int lane = threadIdx.x & 63, wid = threadIdx.x >> 6;
    #pragma unroll
    for (int o = 32; o; o >>= 1) v += __shfl_xor(v, o);
    if (lane == 0) red[wid] = v;
    __syncthreads();
    if (wid == 0) {
        float x = (lane < 16) ? red[lane] : 0.f;
        #pragma unroll
        for (int o = 8; o; o >>= 1) x += __shfl_xor(x, o);
        if (lane == 0) red[0] = x;
    }
    __syncthreads();
    float r = red[0];
    __syncthreads();
    return r;
}

__global__ __launch_bounds__(1024) void loss_kernel(
    const float* __restrict__ lp, const float* __restrict__ mask,
    const float* __restrict__ adv, const float* __restrict__ ref,
    const float* __restrict__ old, float* __restrict__ out) {
    __shared__ float red[16];
    const int s = threadIdx.x;
    float loss_acc = 0.f;
    for (int b = 0; b < 4; ++b) {
        const int i = b * S_ + s;
        const float mk = mask[i];
        const float lpv = lp[i];
        const float lrsum = block_sum((lpv - old[i]) * mk, red);
        const float msum  = block_sum(mk, red);
        const float seqlen = fmaxf(msum, 1.f);
        const float sw = lrsum / seqlen;
        const float c1 = __expf(sw);
        const float c2 = fminf(fmaxf(c1, 1.f - EPS_LOW_C), 1.f + EPS_HIGH_C);
        const float a = adv[b];
        const float pmin = fminf(c1 * a, c2 * a);
        const float d = ref[i] - lpv;
        const float ptl = -pmin + BETA_C * (__expf(d) - d - 1.f);
        const float lsum = block_sum(ptl * mk, red);
        loss_acc += lsum / seqlen;
    }
    if (s == 0) out[0] = loss_acc * (1.f / (float)B_);
}

extern "C" void kernel_launch(void* const* d_in, const int* in_sizes, int n_in,
                              void* d_out, int out_size, void* d_ws, size_t ws_size,
                              hipStream_t stream) {
    const float* x    = (const float*)d_in[0];
    const float* W    = (const float*)d_in[1];
    const float* bias = (const float*)d_in[2];
    const int*   sel  = (const int*)d_in[3];
    const float* mask = (const float*)d_in[4];
    const float* adv  = (const float*)d_in[5];
    const float* ref  = (const float*)d_in[6];
    const float* old  = (const float*)d_in[7];
    float* out = (float*)d_out;

    char* ws = (char*)d_ws;
    unsigned char* Af8 = (unsigned char*)ws;                          // 8,388,608 B
    unsigned char* Wf8 = (unsigned char*)(ws + 8388608);              // 65,536,000 B
    float* partials  = (float*)(ws + 8388608 + 65536000);             // 2,048,000 B
    float* sel_logit = (float*)(ws + 8388608 + 65536000 + 2048000);
    float* lp        = sel_logit + M_;

    cvt_fp8_kernel<<<2048, 256, 0, stream>>>(x, (uint2*)Af8, M_ * H_ / 8, 1.0f);
    cvt_fp8_kernel<<<4096, 256, 0, stream>>>(W, (uint2*)Wf8, V_ * H_ / 8, 32.0f);

    gemm_lse_kernel<<<NRB * NCB, 512, 0, stream>>>(Af8, Wf8, bias, sel, partials, sel_logit);

    reduce_lse_kernel<<<M_, 64, 0, stream>>>(partials, sel_logit, lp);
    loss_kernel<<<1, 1024, 0, stream>>>(lp, mask, adv, ref, old, out);
}

// Round 18
// 574.880 us; speedup vs baseline: 7.2196x; 7.2196x over previous
//
#include <hip/hip_runtime.h>
#include <hip/hip_bf16.h>
#include <hip/hip_fp8.h>

#define BETA_C 0.04f
#define EPS_LOW_C 0.2f
#define EPS_HIGH_C 0.2f

static constexpr int B_ = 4, S_ = 1024, H_ = 2048, V_ = 32000;
static constexpr int M_ = B_ * S_;          // 4096 token rows
static constexpr int BM = 256, BN = 256, BK = 128;   // BK = fp8 elements = bytes
static constexpr int NRB = M_ / BM;         // 16
static constexpr int NCB = V_ / BN;         // 125
static constexpr int NT  = H_ / BK;         // 16 K-steps

typedef __attribute__((ext_vector_type(2))) long long2_t;   // one b128 = 2 fragments
typedef __attribute__((ext_vector_type(4))) float f32x4;

__device__ __forceinline__ unsigned int q8(float v) {
    __hip_fp8_e4m3 t(v);            // OCP e4m3fn, RNE + saturate
    return (unsigned int)t.__x;
}

__device__ __forceinline__ void gload_lds16(const unsigned char* g, char* l) {
    __builtin_amdgcn_global_load_lds(
        (const __attribute__((address_space(1))) unsigned int*)g,
        (__attribute__((address_space(3))) unsigned int*)l, 16, 0, 0);
}

// ---- fp32 -> fp8 e4m3, PRE-TRANSPOSED per 128-elem K-chunk ----
// out byte (lg*32 + s*8 + i) = elem (s*32 + lg*8 + i): one LDS b128 granule then
// holds a lane's TWO k-slice fragments (slices 2(g&1), 2(g&1)+1 for lane-octet g>>1).
__global__ void cvt_fp8_perm_kernel(const float* __restrict__ in, uint4* __restrict__ out,
                                    int ngran, float scale) {
    int g = blockIdx.x * blockDim.x + threadIdx.x;
    int stride = gridDim.x * blockDim.x;
    for (; g < ngran; g += stride) {
        const long base = (long)(g >> 3) * 128;   // element base of this K-chunk
        const int gi = g & 7;
        const float* p0 = in + base + (gi & 1) * 64 + (gi >> 1) * 8;  // slice s0=2(gi&1)
        float4 a0 = *(const float4*)p0;
        float4 a1 = *(const float4*)(p0 + 4);
        float4 b0 = *(const float4*)(p0 + 32);                         // slice s0+1
        float4 b1 = *(const float4*)(p0 + 36);
        uint4 w;
        w.x = q8(a0.x*scale) | (q8(a0.y*scale)<<8) | (q8(a0.z*scale)<<16) | (q8(a0.w*scale)<<24);
        w.y = q8(a1.x*scale) | (q8(a1.y*scale)<<8) | (q8(a1.z*scale)<<16) | (q8(a1.w*scale)<<24);
        w.z = q8(b0.x*scale) | (q8(b0.y*scale)<<8) | (q8(b0.z*scale)<<16) | (q8(b0.w*scale)<<24);
        w.w = q8(b1.x*scale) | (q8(b1.y*scale)<<8) | (q8(b1.z*scale)<<16) | (q8(b1.w*scale)<<24);
        out[g] = w;
    }
}

// ---------------- 256x256 fused GEMM (plain fp8 16x16x32) + exp-sum + sel logit ----
// r10's proven schedule, fp8 payload: half the LDS bytes/FLOP (the measured binding
// pipe). Plain mfma -> acc in AGPRs (no mfma_scale RA spill). 128B rows, 8-slot XOR
// swizzle, 16-rows x 4-slots reads (conflict-free structure since r4).
__global__ __launch_bounds__(512, 2) void gemm_lse_kernel(
    const unsigned char* __restrict__ A,
    const unsigned char* __restrict__ W,
    const float* __restrict__ bias,
    const int* __restrict__ sel,
    float* __restrict__ partials,     // [M][NCB]
    float* __restrict__ sel_logit)    // [M]
{
    __shared__ __attribute__((aligned(128))) char lds[163840]; // A:0,32K  B:64K,96K,128K

    const int bid = blockIdx.x;
    const int swz = (bid & 7) * (NRB * NCB / 8) + (bid >> 3);   // 2000 % 8 == 0: bijective
    const int brow = swz % NRB;
    const int bcol = swz / NRB;
    const int tid  = threadIdx.x;
    const int lane = tid & 63;
    const int wv   = tid >> 6;
    const int wm   = wv >> 2;        // 0..1  row half (128 rows)
    const int wn   = wv & 3;         // 0..3  col quarter (64 cols)
    const int l15  = lane & 15, lg = lane >> 4;

    // ---- LDS read bases: row*128B + swizzled slot (2lg+p)^(row&7); p = slice-pair ----
    int aBase[2], bBase[2];
    #pragma unroll
    for (int p = 0; p < 2; ++p) {
        const int sw = ((2 * lg + p) ^ (l15 & 7)) << 4;
        aBase[p] = (wm * 128 + l15) * 128 + sw;
        bBase[p] = (wn * 64 + l15) * 128 + sw;
    }
    // ---- stage per-lane global byte offsets; source granule inverse-swizzled ----
    int sByte[4];
    #pragma unroll
    for (int i = 0; i < 4; ++i) {
        int c = i * 512 + tid;       // 0..2047 granules of the 32KB tile
        int r = c >> 3;              // 0..255
        int gg = (c & 7) ^ (r & 7);
        sByte[i] = r * 2048 + gg * 16;   // global row stride = 2048 B (fp8)
    }

    const unsigned char* Ab = A + (long)brow * BM * H_;
    const unsigned char* Wb = W + (long)bcol * BN * H_;

    f32x4 acc[8][4] = {};
    long2_t A0[8], A1[8], B0[4], B1[4];   // pair0/pair1 fragments (.x lo-slice, .y hi)

#define STG(gb, bufoff, ktb) \
    { _Pragma("unroll") \
      for (int i_ = 0; i_ < 4; ++i_) \
          gload_lds16((gb) + sByte[i_] + (ktb), \
                      lds + (bufoff) + (i_ * 512 + tid) * 16); }

#define RDP(abuf, bbuf, p, Adst, Bdst) \
    { _Pragma("unroll") \
      for (int mi_ = 0; mi_ < 8; ++mi_) \
          Adst[mi_] = *(const long2_t*)(lds + (abuf) + mi_ * 2048 + aBase[p]); \
      _Pragma("unroll") \
      for (int n_ = 0; n_ < 4; ++n_) \
          Bdst[n_] = *(const long2_t*)(lds + (bbuf) + n_ * 2048 + bBase[p]); }

#define MM(Ar, Br, h) \
    __builtin_amdgcn_s_setprio(1); \
    _Pragma("unroll") \
    for (int mi_ = 0; mi_ < 8; ++mi_) \
    _Pragma("unroll") \
    for (int n_ = 0; n_ < 4; ++n_) \
        acc[mi_][n_] = __builtin_amdgcn_mfma_f32_16x16x32_fp8_fp8( \
            (h) ? Ar[mi_].y : Ar[mi_].x, (h) ? Br[n_].y : Br[n_].x, \
            acc[mi_][n_], 0, 0, 0); \
    __builtin_amdgcn_s_setprio(0);

#define LGKM0   asm volatile("s_waitcnt lgkmcnt(0)" ::: "memory"); \
    __builtin_amdgcn_sched_barrier(0);
#define VMC(n)  asm volatile("s_waitcnt vmcnt(" #n ")" ::: "memory");
#define BAR     { __builtin_amdgcn_s_barrier(); __builtin_amdgcn_sched_barrier(0); }
#define SCB     __builtin_amdgcn_sched_barrier(0);

    // ---- prologue: A(0)->a0, B(0)->b0, B(1)->b1  (12 loads) ----
    STG(Ab, 0, 0)
    STG(Wb, 65536, 0)
    STG(Wb, 98304, 128)
    VMC(4)                      // A(0),B(0) landed; B(1) may fly
    BAR

    #pragma unroll
    for (int t = 0; t < NT; ++t) {
        const int aR  = (t & 1) * 32768;               // A read buf (t)
        const int aW  = ((t + 1) & 1) * 32768;         // A write buf (t+1)
        const int bR  = 65536 + (t % 3) * 32768;       // B read buf (t)
        const int bW  = 65536 + ((t + 2) % 3) * 32768; // B write buf (t+2)
        const int ktA = ((t + 1) * BK) & (H_ - 1);     // bytes; tail wraps (dead-safe)
        const int ktB = ((t + 2) * BK) & (H_ - 1);

        // pair0 reads (12 b128), then stages (vmcnt only)
        RDP(aR, bR, 0, A0, B0)
        SCB
        STG(Ab, aW, ktA)
        STG(Wb, bW, ktB)
        LGKM0               // pair0 done
        MM(A0, B0, 0)       // slice 0
        RDP(aR, bR, 1, A1, B1)   // pair1 drains under slice-1 cluster
        SCB
        MM(A0, B0, 1)       // slice 1
        LGKM0               // pair1 done; all step-t LDS reads drained before barrier
        MM(A1, B1, 0)       // slice 2
        MM(A1, B1, 1)       // slice 3
        // boundary: newest 4 vm-ops = B(t+2); forces A(t+1), B(t+1) landed.
        VMC(4)
        BAR
    }

    VMC(0)
    __syncthreads();

    // ---- epilogue: dequant (x1/32), bias, exp, row partial sums, selected logit ----
    float* sums = (float*)lds;                     // [256][4], LDS now free
    const int colb = bcol * BN + wn * 64 + l15;    // + n*16
    float bv[4];
    #pragma unroll
    for (int n = 0; n < 4; ++n) bv[n] = bias[colb + n * 16];

    #pragma unroll
    for (int m = 0; m < 8; ++m) {
        #pragma unroll
        for (int j = 0; j < 4; ++j) {
            const long grow = (long)brow * BM + wm * 128 + m * 16 + lg * 4 + j;
            const int stok = sel[grow];
            float s = 0.f;
            #pragma unroll
            for (int n = 0; n < 4; ++n) {
                float logit = acc[m][n][j] * 0.03125f + bv[n];
                s += __expf(logit);
                if (stok == colb + n * 16) sel_logit[grow] = logit;
            }
            s += __shfl_xor(s, 1); s += __shfl_xor(s, 2);
            s += __shfl_xor(s, 4); s += __shfl_xor(s, 8);
            if (l15 == 0) sums[(wm * 128 + m * 16 + lg * 4 + j) * 4 + wn] = s;
        }
    }
    __syncthreads();
    if (tid < BM) {
        float tot = sums[tid * 4 + 0] + sums[tid * 4 + 1] + sums[tid * 4 + 2] + sums[tid * 4 + 3];
        partials[((long)brow * BM + tid) * NCB + bcol] = tot;
    }
#undef STG
#undef RDP
#undef MM
#undef LGKM0
#undef VMC
#undef BAR
#undef SCB
}

// ---------------- per-row reduce: partials -> per-token logp ----------------
__global__ void reduce_lse_kernel(const float* __restrict__ partials,
                                  const float* __restrict__ sel_logit,
                                  float* __restrict__ lp) {
    const int row = blockIdx.x;
    const int lane = threadIdx.x;   // 64
    float s = 0.f;
    for (int i = lane; i < NCB; i += 64) s += partials[(long)row * NCB + i];
    #pragma unroll
    for (int o = 32; o; o >>= 1) s += __shfl_xor(s, o);
    if (lane == 0) lp[row] = sel_logit[row] - __logf(s);
}

// ---------------- final GSPO loss (one block) ----------------
__device__ __forceinline__ float block_sum(float v, float* red) {
    const int lane = threadIdx.x & 63, wid = threadIdx.x >> 6;
    #pragma unroll
    for (int o = 32; o; o >>= 1) v += __shfl_xor(v, o);
    if (lane == 0) red[wid] = v;
    __syncthreads();
    if (wid == 0) {
        float x = (lane < 16) ? red[lane] : 0.f;
        #pragma unroll
        for (int o = 8; o; o >>= 1) x += __shfl_xor(x, o);
        if (lane == 0) red[0] = x;
    }
    __syncthreads();
    float r = red[0];
    __syncthreads();
    return r;
}

__global__ __launch_bounds__(1024) void loss_kernel(
    const float* __restrict__ lp, const float* __restrict__ mask,
    const float* __restrict__ adv, const float* __restrict__ ref,
    const float* __restrict__ old, float* __restrict__ out) {
    __shared__ float red[16];
    const int s = threadIdx.x;
    float loss_acc = 0.f;
    for (int b = 0; b < 4; ++b) {
        const int i = b * S_ + s;
        const float mk = mask[i];
        const float lpv = lp[i];
        const float lrsum = block_sum((lpv - old[i]) * mk, red);
        const float msum  = block_sum(mk, red);
        const float seqlen = fmaxf(msum, 1.f);
        const float sw = lrsum / seqlen;
        const float c1 = __expf(sw);
        const float c2 = fminf(fmaxf(c1, 1.f - EPS_LOW_C), 1.f + EPS_HIGH_C);
        const float a = adv[b];
        const float pmin = fminf(c1 * a, c2 * a);
        const float d = ref[i] - lpv;
        const float ptl = -pmin + BETA_C * (__expf(d) - d - 1.f);
        const float lsum = block_sum(ptl * mk, red);
        loss_acc += lsum / seqlen;
    }
    if (s == 0) out[0] = loss_acc * (1.f / (float)B_);
}

extern "C" void kernel_launch(void* const* d_in, const int* in_sizes, int n_in,
                              void* d_out, int out_size, void* d_ws, size_t ws_size,
                              hipStream_t stream) {
    const float* x    = (const float*)d_in[0];
    const float* W    = (const float*)d_in[1];
    const float* bias = (const float*)d_in[2];
    const int*   sel  = (const int*)d_in[3];
    const float* mask = (const float*)d_in[4];
    const float* adv  = (const float*)d_in[5];
    const float* ref  = (const float*)d_in[6];
    const float* old  = (const float*)d_in[7];
    float* out = (float*)d_out;

    char* ws = (char*)d_ws;
    unsigned char* Af8 = (unsigned char*)ws;                          // 8,388,608 B
    unsigned char* Wf8 = (unsigned char*)(ws + 8388608);              // 65,536,000 B
    float* partials  = (float*)(ws + 8388608 + 65536000);             // 2,048,000 B
    float* sel_logit = (float*)(ws + 8388608 + 65536000 + 2048000);
    float* lp        = sel_logit + M_;

    cvt_fp8_perm_kernel<<<2048, 256, 0, stream>>>(x, (uint4*)Af8, M_ * H_ / 16, 1.0f);
    cvt_fp8_perm_kernel<<<4096, 256, 0, stream>>>(W, (uint4*)Wf8, V_ * H_ / 16, 32.0f);

    gemm_lse_kernel<<<NRB * NCB, 512, 0, stream>>>(Af8, Wf8, bias, sel, partials, sel_logit);

    reduce_lse_kernel<<<M_, 64, 0, stream>>>(partials, sel_logit, lp);
    loss_kernel<<<1, 1024, 0, stream>>>(lp, mask, adv, ref, old, out);
}